// Round 6
// baseline (170.963 us; speedup 1.0000x reference)
//
#include <hip/hip_runtime.h>

#define HH 2048
#define NPIX (HH * HH)      // 4194304
#define NBINS 256
#define NRBINS 512          // refined bins: r = hb + tb, r in [0,510]
#define NQ (NPIX / 4)       // 1048576 float4 quads

#define THREADS 512
#define SRC_BLOCKS 1024
#define TAR_BLOCKS 1024
#define GRID (SRC_BLOCKS + TAR_BLOCKS)
#define SRC_CHUNK (NQ / SRC_BLOCKS)      // 1024 quads, contiguous per block
#define TAR_CHUNK (NQ / TAR_BLOCKS)      // 1024
#define SRC_ITERS (SRC_CHUNK / THREADS)  // 2
#define TAR_ITERS (TAR_CHUNK / THREADS)  // 2

#define CNT_SHIFT 42
#define FRAC_MASK ((1ULL << CNT_SHIFT) - 1)

// workspace (zeroed each launch):
//   u64 gpk[3][512] : refined src stats (count<<42 | sum floor(frac*2^22))
//   u32 ght[3][256] : tar masked hist
#define GPK_WORDS (3 * NRBINS)
#define GHT_WORDS (3 * NBINS)
#define WS_ZERO_BYTES (GPK_WORDS * 8 + GHT_WORDS * 4)

__device__ __forceinline__ float denorm255(float x) {
    // matches clip((x+1)*0.5, 0, 1) * 255 in fp32
    return fminf(fmaxf((x + 1.0f) * 0.5f, 0.0f), 1.0f) * 255.0f;
}

__global__ __launch_bounds__(THREADS, 8) void fused_hist(
        const float* __restrict__ in, const float* __restrict__ tarp,
        const float* __restrict__ ms, const float* __restrict__ mt,
        unsigned long long* __restrict__ gpk, unsigned* __restrict__ ght) {
    __shared__ unsigned long long lpk[3 * NRBINS];  // 12 KB (tar blocks alias as u32)
    const float BSCALE = 256.0f / 255.0f;  // same nearest-f32 constant as jnp
    const float FSCALE = 4194304.0f;       // 2^22

    if (blockIdx.x < SRC_BLOCKS) {
        // ---- src blocks: refined histogram (count + frac) over 4 streams ----
        for (int i = threadIdx.x; i < 3 * NRBINS; i += THREADS) lpk[i] = 0ULL;
        __syncthreads();
        const int base = blockIdx.x * SRC_CHUNK + threadIdx.x;
        #pragma unroll
        for (int s = 0; s < SRC_ITERS; ++s) {
            const int idx = base + s * THREADS;
            float4 m4 = ((const float4*)ms)[idx];
            float4 a0 = ((const float4*)(in))[idx];
            float4 a1 = ((const float4*)(in + NPIX))[idx];
            float4 a2 = ((const float4*)(in + 2 * NPIX))[idx];
            const float mv[4] = {m4.x, m4.y, m4.z, m4.w};
            const float av[3][4] = {{a0.x, a0.y, a0.z, a0.w},
                                    {a1.x, a1.y, a1.z, a1.w},
                                    {a2.x, a2.y, a2.z, a2.w}};
            #pragma unroll
            for (int ch = 0; ch < 3; ++ch) {
                #pragma unroll
                for (int k = 0; k < 4; ++k) {
                    if (mv[k] != 0.0f) {  // masked lanes issue no bank-RMW
                        float v = denorm255(av[ch][k]);
                        int hb = min((int)(v * BSCALE), NBINS - 1);  // floor, v>=0
                        int tb = (int)v;                             // [0,255]
                        // v - tb Sterbenz-exact; *2^22 exact; trunc err < 2^-22
                        unsigned fr = (unsigned)((v - (float)tb) * FSCALE);
                        atomicAdd(&lpk[ch * NRBINS + hb + tb],
                                  (1ULL << CNT_SHIFT) | (unsigned long long)fr);
                    }
                }
            }
        }
        __syncthreads();
        for (int i = threadIdx.x; i < 3 * NRBINS; i += THREADS) {
            unsigned long long p = lpk[i];
            if (p) atomicAdd(&gpk[i], p);
        }
    } else {
        // ---- tar blocks: plain masked histogram over 4 streams ----
        unsigned* lht = (unsigned*)lpk;  // 3 KB of the 12 KB
        for (int i = threadIdx.x; i < 3 * NBINS; i += THREADS) lht[i] = 0u;
        __syncthreads();
        const int base = (blockIdx.x - SRC_BLOCKS) * TAR_CHUNK + threadIdx.x;
        #pragma unroll
        for (int s = 0; s < TAR_ITERS; ++s) {
            const int idx = base + s * THREADS;
            float4 t4 = ((const float4*)mt)[idx];
            float4 b0 = ((const float4*)(tarp))[idx];
            float4 b1 = ((const float4*)(tarp + NPIX))[idx];
            float4 b2 = ((const float4*)(tarp + 2 * NPIX))[idx];
            const float tv[4] = {t4.x, t4.y, t4.z, t4.w};
            const float bv[3][4] = {{b0.x, b0.y, b0.z, b0.w},
                                    {b1.x, b1.y, b1.z, b1.w},
                                    {b2.x, b2.y, b2.z, b2.w}};
            #pragma unroll
            for (int ch = 0; ch < 3; ++ch) {
                #pragma unroll
                for (int k = 0; k < 4; ++k) {
                    if (tv[k] != 0.0f) {
                        float w = denorm255(bv[ch][k]);
                        int wb = min((int)(w * BSCALE), NBINS - 1);
                        atomicAdd(&lht[ch * NBINS + wb], 1u);
                    }
                }
            }
        }
        __syncthreads();
        for (int i = threadIdx.x; i < 3 * NBINS; i += THREADS) {
            unsigned h = lht[i];
            if (h) atomicAdd(&ght[i], h);
        }
    }
}

__global__ __launch_bounds__(NBINS) void table_loss(
        const unsigned long long* __restrict__ gpk,
        const unsigned* __restrict__ ght, float* __restrict__ out) {
    __shared__ float cdf[6][NBINS];
    __shared__ float tot[6];
    const int t = threadIdx.x;  // 0..255

    // decode refined bins: hist bin t gets counts from r=2t and r=2t-1
    unsigned long long pe[3], po[3];
    #pragma unroll
    for (int ch = 0; ch < 3; ++ch) {
        pe[ch] = gpk[ch * NRBINS + 2 * t];
        po[ch] = gpk[ch * NRBINS + 2 * t + 1];
        unsigned long long pp = (t > 0) ? gpk[ch * NRBINS + 2 * t - 1] : 0ULL;
        cdf[ch][t] = (float)((pe[ch] >> CNT_SHIFT) + (pp >> CNT_SHIFT));
        cdf[3 + ch][t] = (float)ght[ch * NBINS + t];
    }
    __syncthreads();
    // Hillis-Steele inclusive scan; partials are integers < 2^24 -> exact
    #pragma unroll
    for (int off = 1; off < NBINS; off <<= 1) {
        float add[6];
        #pragma unroll
        for (int j = 0; j < 6; ++j) add[j] = (t >= off) ? cdf[j][t - off] : 0.0f;
        __syncthreads();
        #pragma unroll
        for (int j = 0; j < 6; ++j) cdf[j][t] += add[j];
        __syncthreads();
    }
    if (t < 6) tot[t] = fmaxf(cdf[t][NBINS - 1], 1.0f);
    __syncthreads();
    #pragma unroll
    for (int j = 0; j < 6; ++j) cdf[j][t] = cdf[j][t] / tot[j];
    __syncthreads();

    double lsum = 0.0;
    #pragma unroll
    for (int ch = 0; ch < 3; ++ch) {
        const float d = cdf[ch][t];
        const float* ref = cdf[3 + ch];
        // searchsorted side='left': first idx with ref[idx] >= d
        int lo = 0, hi = NBINS;
        while (lo < hi) {
            int mid = (lo + hi) >> 1;
            if (ref[mid] < d) lo = mid + 1; else hi = mid;
        }
        int cand = min(max(lo, 1), NBINS - 1);
        int T = (ref[cand - 1] <= d && ref[cand] >= d) ? cand : t;
        if (t == 0) T = 0;
        if (t == NBINS - 1) T = NBINS - 1;

        // trunc-bin t stats: r=2t and r=2t+1
        const int b = t;
        const double c =
            (double)((pe[ch] >> CNT_SHIFT) + (po[ch] >> CNT_SHIFT));
        const double F =
            (double)((pe[ch] & FRAC_MASK) + (po[ch] & FRAC_MASK)) *
            (1.0 / 4194304.0);
        // pixels with trunc(v)=b: |v-T| = (b-T)+f if T<=b else (T-b)-f
        lsum += (T <= b) ? (c * (double)(b - T) + F)
                         : (c * (double)(T - b) - F);
    }
    // reduce doubles across 4 waves
    #pragma unroll
    for (int off = 32; off; off >>= 1) lsum += __shfl_down(lsum, off, 64);
    __shared__ double wsum[4];
    if ((t & 63) == 0) wsum[t >> 6] = lsum;
    __syncthreads();
    if (t == 0)
        out[0] = (float)((wsum[0] + wsum[1] + wsum[2] + wsum[3]) /
                         (double)(3 * NPIX));
}

extern "C" void kernel_launch(void* const* d_in, const int* in_sizes, int n_in,
                              void* d_out, int out_size, void* d_ws, size_t ws_size,
                              hipStream_t stream) {
    const float* in  = (const float*)d_in[0];
    const float* tar = (const float*)d_in[1];
    const float* ms  = (const float*)d_in[2];
    const float* mt  = (const float*)d_in[3];
    float* out = (float*)d_out;

    unsigned long long* gpk = (unsigned long long*)d_ws;
    unsigned* ght = (unsigned*)((char*)d_ws + GPK_WORDS * 8);

    hipMemsetAsync(d_ws, 0, WS_ZERO_BYTES, stream);
    fused_hist<<<GRID, THREADS, 0, stream>>>(in, tar, ms, mt, gpk, ght);
    table_loss<<<1, NBINS, 0, stream>>>(gpk, ght, out);
}